// Round 13
// baseline (209.784 us; speedup 1.0000x reference)
//
#include <hip/hip_runtime.h>

#define T_ 4
#define B_ 32
#define C_ 384
#define N_ 256
#define HEADS_ 8
#define DH_ 48
#define EPS_ 1e-5f
#define NW_ (C_*C_)

typedef _Float16 f16;
typedef __attribute__((ext_vector_type(8))) _Float16 f16x8;
typedef __attribute__((ext_vector_type(16))) float f32x16;

#define PSCALE     4096.0f
#define PSCALE_INV (1.0f/4096.0f)
#define SPIKE_BYTE 0x3Cu   // high byte of f16 1.0

// unpack 4 spike bytes (0x3C/0x00) -> 2 u32 holding 4 f16 (0x3C00/0x0000)
__device__ __forceinline__ void unpack4(unsigned int w, unsigned int& lo, unsigned int& hi) {
#if defined(__has_builtin) && __has_builtin(__builtin_amdgcn_perm)
    lo = __builtin_amdgcn_perm(w, w, 0x010C000Cu);  // [0, b0, 0, b1]
    hi = __builtin_amdgcn_perm(w, w, 0x030C020Cu);  // [0, b2, 0, b3]
#else
    lo = ((w & 0xFFu) << 8) | ((w & 0xFF00u) << 16);
    hi = ((w & 0x00FF0000u) >> 8) | (w & 0xFF000000u);
#endif
}

// expand 16 spike bytes (uint4) -> 32 f16 bytes (2x uint4)
__device__ __forceinline__ void unpack16(uint4 w, uint4& o0, uint4& o1) {
    unpack4(w.x, o0.x, o0.y); unpack4(w.y, o0.z, o0.w);
    unpack4(w.z, o1.x, o1.y); unpack4(w.w, o1.z, o1.w);
}

// split one f32 weight -> (a, b) f16 planes
__device__ __forceinline__ void wsplit(float w, f16& a, f16& b) {
    a = (f16)w; b = (f16)((w - (float)a) * PSCALE);
}

// ---------------------------------------------------------------------------
// Kernel 1: input LIF (z<32) + weight split over 144 blocks (z in [32,44)).
// (round-11 version, validated)
// ---------------------------------------------------------------------------
__global__ __launch_bounds__(256)
void prep_kernel(const float* __restrict__ x, unsigned char* __restrict__ s,
                 const float* __restrict__ qw, const float* __restrict__ kw,
                 const float* __restrict__ pw,
                 f16* __restrict__ q2, f16* __restrict__ k2, f16* __restrict__ p2)
{
    if (blockIdx.z >= 32) {
        const int blid = ((blockIdx.z - 32) * 3 + blockIdx.y) * 4 + blockIdx.x; // 0..143
        const int i4 = blid * 256 + threadIdx.x;   // 0..36863 == NW_/4 - 1
        {
            float4 w = ((const float4*)qw)[i4];
            union { f16 h[4]; uint2 u; } a, b;
            wsplit(w.x, a.h[0], b.h[0]); wsplit(w.y, a.h[1], b.h[1]);
            wsplit(w.z, a.h[2], b.h[2]); wsplit(w.w, a.h[3], b.h[3]);
            *(uint2*)&q2[(size_t)i4 * 4] = a.u;
            *(uint2*)&q2[NW_ + (size_t)i4 * 4] = b.u;
        }
        {
            float4 w = ((const float4*)kw)[i4];
            union { f16 h[4]; uint2 u; } a, b;
            wsplit(w.x, a.h[0], b.h[0]); wsplit(w.y, a.h[1], b.h[1]);
            wsplit(w.z, a.h[2], b.h[2]); wsplit(w.w, a.h[3], b.h[3]);
            *(uint2*)&k2[(size_t)i4 * 4] = a.u;
            *(uint2*)&k2[NW_ + (size_t)i4 * 4] = b.u;
        }
        {
            float4 w = ((const float4*)pw)[i4];
            union { f16 h[4]; uint2 u; } a, b;
            wsplit(w.x, a.h[0], b.h[0]); wsplit(w.y, a.h[1], b.h[1]);
            wsplit(w.z, a.h[2], b.h[2]); wsplit(w.w, a.h[3], b.h[3]);
            *(uint2*)&p2[(size_t)i4 * 4] = a.u;
            *(uint2*)&p2[NW_ + (size_t)i4 * 4] = b.u;
        }
        return;
    }

    const int tid = threadIdx.x;
    const int ng = tid & 15;                     // n-group
    const int cg = tid >> 4;                     // 0..15
    const int n4 = blockIdx.x * 64 + ng * 4;     // 4 consecutive n
    const int c0 = blockIdx.y * 128 + cg * 8;    // 8 consecutive c
    const int b  = blockIdx.z;

    float v[8][4];
#pragma unroll
    for (int i = 0; i < 8; ++i)
#pragma unroll
        for (int j = 0; j < 4; ++j) v[i][j] = 0.f;

#pragma unroll
    for (int t = 0; t < T_; ++t) {
        const float* xt = x + (((size_t)t * B_ + b) * C_) * N_;
        float4 xv[8];
#pragma unroll
        for (int i = 0; i < 8; ++i)
            xv[i] = *(const float4*)&xt[(size_t)(c0 + i) * N_ + n4];
#pragma unroll
        for (int j = 0; j < 4; ++j) {
            union { unsigned char bb[8]; uint2 u; } u;
#pragma unroll
            for (int i = 0; i < 8; ++i) {
                float xa = (j == 0) ? xv[i].x : (j == 1) ? xv[i].y
                         : (j == 2) ? xv[i].z : xv[i].w;
                float vv = 0.5f * v[i][j] + xa;
                int sp = (vv >= 1.0f) ? 1 : 0;
                v[i][j] = sp ? 0.f : vv;
                u.bb[i] = sp ? (unsigned char)SPIKE_BYTE : (unsigned char)0;
            }
            unsigned char* dst = s + (((size_t)t * B_ + b) * N_ + n4 + j) * (size_t)C_ + c0;
            *(uint2*)dst = u.u;
        }
    }
}

// ---------------------------------------------------------------------------
// Kernel 2: q/k GEMM + BN + fully in-register LIF (round-11 exact, 51 us).
// BK=64, 2-barrier K-step with register prefetch; sigma row permutation;
// u8 spikes in/out, both spike buffers (t,b,n,C).
// ---------------------------------------------------------------------------
__global__ __launch_bounds__(256)
void qk_gemm_lif_kernel(const f16* __restrict__ Wq, const f16* __restrict__ Wk,
                        const unsigned char* __restrict__ S,
                        const float* __restrict__ qg, const float* __restrict__ qb,
                        const float* __restrict__ qm, const float* __restrict__ qv,
                        const float* __restrict__ kg, const float* __restrict__ kb,
                        const float* __restrict__ km, const float* __restrict__ kv,
                        unsigned char* __restrict__ q_spk,
                        unsigned char* __restrict__ k_spk)
{
    __shared__ __align__(16) char smem[36864];
    f16 (*As)[72]      = reinterpret_cast<f16(*)[72]>(smem);            // [128][72]
    f16 (*Bs)[64][72]  = reinterpret_cast<f16(*)[64][72]>(smem + 18432);// [2][64][72]

    const int tid  = threadIdx.x;
    const int lane = tid & 63;
    const int wave = tid >> 6;
    const int wm = wave & 1, wd = wave >> 1;
    const int l31 = lane & 31;
    const int lhi = lane >> 5;

    const int mb = blockIdx.x;            // 0..255
    const int b  = mb >> 3;
    const int n0 = (mb & 7) * 32;
    const int dp0 = blockIdx.y * 64;      // 0..704
    const int path = (dp0 >= C_) ? 1 : 0; // 0=q 1=k
    const int d0 = dp0 - path * C_;

    const f16* W = path ? Wk : Wq;
    const float* g_  = path ? kg : qg;
    const float* be_ = path ? kb : qb;
    const float* m_  = path ? km : qm;
    const float* va_ = path ? kv : qv;
    unsigned char* spk = path ? k_spk : q_spk;

    const int dcol = d0 + wd * 32 + l31;
    const float inv = g_[dcol] / sqrtf(va_[dcol] + EPS_);
    const float add = be_[dcol] - m_[dcol] * inv;

    // staging map (round-0 global order: wave covers 32 consecutive n, one t)
    const int ar = tid >> 1;              // 0..127: content (t=ar>>5, n=ar&31)
    const int ah = (tid & 1) * 32;        // channel-half offset
    const int at = ar >> 5;
    const int anl = ar & 31;
    const unsigned char* arow = S + (((size_t)at * B_ + b) * N_ + n0 + anl) * (size_t)C_;
    // physical LDS row: sigma(4n+t) = 4n + ((t + (n>>1)) & 3)
    const int aps = 4 * anl + ((at + (anl >> 1)) & 3);

    const int bp = tid >> 7;              // plane
    const int brr = (tid >> 1) & 63;      // d row
    const int bh = (tid & 1) * 32;
    const f16* brow = W + (size_t)bp * NW_ + (size_t)(d0 + brr) * C_;

    // fragment-read rows: sigma(wm*64+ms*32+l31)
    const int abase = 4 * (l31 >> 2) + ((l31 + (l31 >> 3)) & 3);
    const f16* pa0 = &As[wm * 64 + abase][0];   // msub 0
    const f16* pa1 = pa0 + 32 * 72;             // msub 1 (+32 physical rows)

    f32x16 acc[2][2];                     // [msub][plane]
#pragma unroll
    for (int ms = 0; ms < 2; ++ms)
#pragma unroll
        for (int p = 0; p < 2; ++p)
#pragma unroll
            for (int r = 0; r < 16; ++r) acc[ms][p][r] = 0.f;

    // prologue prefetch (tile 0)
    uint4 ra0 = *(const uint4*)(arow + ah);
    uint4 ra1 = *(const uint4*)(arow + ah + 16);
    uint4 rb0 = *(const uint4*)(brow + bh);
    uint4 rb1 = *(const uint4*)(brow + bh + 8);
    uint4 rb2 = *(const uint4*)(brow + bh + 16);
    uint4 rb3 = *(const uint4*)(brow + bh + 24);

#pragma unroll
    for (int ic = 0; ic < 6; ++ic) {
        __syncthreads();                  // prev-tile reads done; drains prefetch
        {
            uint4 o0, o1;
            unpack16(ra0, o0, o1);
            *(uint4*)&As[aps][ah]      = o0;
            *(uint4*)&As[aps][ah + 8]  = o1;
            unpack16(ra1, o0, o1);
            *(uint4*)&As[aps][ah + 16] = o0;
            *(uint4*)&As[aps][ah + 24] = o1;
            *(uint4*)&Bs[bp][brr][bh]      = rb0;
            *(uint4*)&Bs[bp][brr][bh + 8]  = rb1;
            *(uint4*)&Bs[bp][brr][bh + 16] = rb2;
            *(uint4*)&Bs[bp][brr][bh + 24] = rb3;
        }
        __syncthreads();                  // writes visible
        if (ic < 5) {                     // issue next-tile loads: in flight during MFMA
            const int kn = ic * 64 + 64;
            ra0 = *(const uint4*)(arow + kn + ah);
            ra1 = *(const uint4*)(arow + kn + ah + 16);
            rb0 = *(const uint4*)(brow + kn + bh);
            rb1 = *(const uint4*)(brow + kn + bh + 8);
            rb2 = *(const uint4*)(brow + kn + bh + 16);
            rb3 = *(const uint4*)(brow + kn + bh + 24);
        }
#pragma unroll
        for (int kk = 0; kk < 4; ++kk) {
            const int ko = kk * 16 + lhi * 8;
            f16x8 a0 = *(const f16x8*)(pa0 + ko);
            f16x8 a1 = *(const f16x8*)(pa1 + ko);
            f16x8 b0 = *(const f16x8*)&Bs[0][wd * 32 + l31][ko];
            f16x8 b1 = *(const f16x8*)&Bs[1][wd * 32 + l31][ko];
            acc[0][0] = __builtin_amdgcn_mfma_f32_32x32x16_f16(a0, b0, acc[0][0], 0, 0, 0);
            acc[1][0] = __builtin_amdgcn_mfma_f32_32x32x16_f16(a1, b0, acc[1][0], 0, 0, 0);
            acc[0][1] = __builtin_amdgcn_mfma_f32_32x32x16_f16(a0, b1, acc[0][1], 0, 0, 0);
            acc[1][1] = __builtin_amdgcn_mfma_f32_32x32x16_f16(a1, b1, acc[1][1], 0, 0, 0);
        }
    }

    // in-register BN + LIF + u8 spike store (t == r&3; no LDS, no barrier).
#pragma unroll
    for (int ms = 0; ms < 2; ++ms)
#pragma unroll
    for (int g = 0; g < 4; ++g) {
        const int n = n0 + wm * 16 + ms * 8 + 2 * g + lhi;
        float v = 0.f;
#pragma unroll
        for (int t = 0; t < 4; ++t) {
            const int r = g * 4 + t;
            float val = (acc[ms][0][r] + acc[ms][1][r] * PSCALE_INV) * inv + add;
            float vv = 0.5f * v + val;
            int sp = (vv >= 1.0f) ? 1 : 0;
            v = sp ? 0.f : vv;
            spk[(((size_t)t * B_ + b) * N_ + n) * C_ + dcol] =
                sp ? (unsigned char)SPIKE_BYTE : (unsigned char)0;
        }
    }
}

// ---------------------------------------------------------------------------
// Kernel 3: fused head-sum + decayed memory + attention LIF (u8 spikes,
// (t,b,n,C) layout -- round-11 exact).
// ---------------------------------------------------------------------------
__global__ __launch_bounds__(256)
void head_attn_kernel(const unsigned char* __restrict__ q_spk,
                      const float* __restrict__ alpha_p,
                      unsigned char* __restrict__ attn)
{
    int i = blockIdx.x * 256 + threadIdx.x;   // B*H*N = 65536
    int n = i & (N_ - 1);
    int h = (i >> 8) & (HEADS_ - 1);
    int b = i >> 11;
    const float alpha = alpha_p[0];
    const int stride = B_ * HEADS_ * N_;
    float M = 0.f, v = 0.f, Sprev = 0.f;
#pragma unroll
    for (int t = 0; t < T_; ++t) {
        const uint4* p = (const uint4*)(q_spk + (((size_t)(t * B_ + b) * N_) + n) * C_ + h * DH_);
        int cnt = 0;
#pragma unroll
        for (int j = 0; j < 3; ++j) {          // 48 bytes = 3 x uint4
            uint4 w = p[j];
            cnt += __popc(w.x & 0x04040404u) + __popc(w.y & 0x04040404u)
                 + __popc(w.z & 0x04040404u) + __popc(w.w & 0x04040404u);
        }
        float Sqt = (float)cnt;
        if (t == 0) M = Sqt;
        else        M = alpha * M + (1.f - alpha) * Sprev;
        float qsum = M + Sqt;
        float vv = 0.5f * v + qsum;
        unsigned char sp = (vv >= 0.5f) ? 1 : 0;
        v = sp ? 0.f : vv;
        attn[(size_t)t * stride + i] = sp;
        Sprev = Sqt;
    }
}

// ---------------------------------------------------------------------------
// Kernel 4: proj GEMM (round-8 K-loop + round-12 epilogue): acc -> padded
// [64][129] f32 LDS transpose tile -> fully coalesced float4 stores.
// ---------------------------------------------------------------------------
__global__ __launch_bounds__(256)
void proj_gemm_kernel(const f16* __restrict__ Wp,
                      const unsigned char* __restrict__ K8,
                      const unsigned char* __restrict__ attn,
                      const float* __restrict__ bias,
                      const float* __restrict__ gamma, const float* __restrict__ beta,
                      const float* __restrict__ mean,  const float* __restrict__ var,
                      float* __restrict__ out)
{
    __shared__ __align__(16) char smem[36864];
    f16 (*As)[72]     = reinterpret_cast<f16(*)[72]>(smem);
    f16 (*Bs)[64][72] = reinterpret_cast<f16(*)[64][72]>(smem + 18432);
    float (*Pt)[129]  = reinterpret_cast<float(*)[129]>(smem);   // reuse: [64][129]

    const int tid  = threadIdx.x;
    const int lane = tid & 63;
    const int wave = tid >> 6;
    const int wm = wave & 1, wd = wave >> 1;
    const int l31 = lane & 31;
    const int lhi = lane >> 5;

    const int mb = blockIdx.x;            // 0..255
    const int tb = mb >> 1;
    const int n0 = (mb & 1) * 128;
    const int d0 = blockIdx.y * 64;

    const int dcol = d0 + wd * 32 + l31;
    const float iv = gamma[dcol] / sqrtf(var[dcol] + EPS_);
    const float ad = beta[dcol] - mean[dcol] * iv + bias[dcol] * iv;

    // A reg-stage map: 2 threads/row, 4 chunks of 8 channels each
    const int ar = tid >> 1;              // 0..127
    const int ah = (tid & 1) * 32;
    const int an = n0 + ar;
    const unsigned char* arow = K8 + ((size_t)tb * N_ + an) * (size_t)C_;
    const unsigned char* At = attn + (size_t)tb * HEADS_ * N_;

    const int bp = tid >> 7;
    const int brr = (tid >> 1) & 63;
    const int bh = (tid & 1) * 32;
    const f16* brow = Wp + (size_t)bp * NW_ + (size_t)(d0 + brr) * C_;

    f32x16 acc[2][2];
#pragma unroll
    for (int ms = 0; ms < 2; ++ms)
#pragma unroll
        for (int p = 0; p < 2; ++p)
#pragma unroll
            for (int r = 0; r < 16; ++r) acc[ms][p][r] = 0.f;

    // prologue prefetch (tile 0)
    uint2 wa0, wa1, wa2, wa3;
    unsigned char am0, am1, am2, am3;
    uint4 rb0, rb1, rb2, rb3;
    {
        const int c0 = ah;
        am0 = At[(size_t)((c0     ) / DH_) * N_ + an]; wa0 = *(const uint2*)(arow + c0);
        am1 = At[(size_t)((c0 +  8) / DH_) * N_ + an]; wa1 = *(const uint2*)(arow + c0 + 8);
        am2 = At[(size_t)((c0 + 16) / DH_) * N_ + an]; wa2 = *(const uint2*)(arow + c0 + 16);
        am3 = At[(size_t)((c0 + 24) / DH_) * N_ + an]; wa3 = *(const uint2*)(arow + c0 + 24);
        rb0 = *(const uint4*)(brow + bh);
        rb1 = *(const uint4*)(brow + bh + 8);
        rb2 = *(const uint4*)(brow + bh + 16);
        rb3 = *(const uint4*)(brow + bh + 24);
    }

#pragma unroll
    for (int ic = 0; ic < 6; ++ic) {
        __syncthreads();
        {
            uint2 w;
            uint4 o;
            w = am0 ? wa0 : make_uint2(0u, 0u);
            unpack4(w.x, o.x, o.y); unpack4(w.y, o.z, o.w);
            *(uint4*)&As[ar][ah] = o;
            w = am1 ? wa1 : make_uint2(0u, 0u);
            unpack4(w.x, o.x, o.y); unpack4(w.y, o.z, o.w);
            *(uint4*)&As[ar][ah + 8] = o;
            w = am2 ? wa2 : make_uint2(0u, 0u);
            unpack4(w.x, o.x, o.y); unpack4(w.y, o.z, o.w);
            *(uint4*)&As[ar][ah + 16] = o;
            w = am3 ? wa3 : make_uint2(0u, 0u);
            unpack4(w.x, o.x, o.y); unpack4(w.y, o.z, o.w);
            *(uint4*)&As[ar][ah + 24] = o;
            *(uint4*)&Bs[bp][brr][bh]      = rb0;
            *(uint4*)&Bs[bp][brr][bh + 8]  = rb1;
            *(uint4*)&Bs[bp][brr][bh + 16] = rb2;
            *(uint4*)&Bs[bp][brr][bh + 24] = rb3;
        }
        __syncthreads();
        if (ic < 5) {
            const int kn = ic * 64 + 64;
            const int c0 = kn + ah;
            am0 = At[(size_t)((c0     ) / DH_) * N_ + an]; wa0 = *(const uint2*)(arow + c0);
            am1 = At[(size_t)((c0 +  8) / DH_) * N_ + an]; wa1 = *(const uint2*)(arow + c0 + 8);
            am2 = At[(size_t)((c0 + 16) / DH_) * N_ + an]; wa2 = *(const uint2*)(arow + c0 + 16);
            am3 = At[(size_t)((c0 + 24) / DH_) * N_ + an]; wa3 = *(const uint2*)(arow + c0 + 24);
            rb0 = *(const uint4*)(brow + kn + bh);
            rb1 = *(const uint4*)(brow + kn + bh + 8);
            rb2 = *(const uint4*)(brow + kn + bh + 16);
            rb3 = *(const uint4*)(brow + kn + bh + 24);
        }
#pragma unroll
        for (int kk = 0; kk < 4; ++kk) {
            const int ko = kk * 16 + lhi * 8;
            f16x8 a0 = *(const f16x8*)&As[wm * 64 + l31][ko];
            f16x8 a1 = *(const f16x8*)&As[wm * 64 + 32 + l31][ko];
            f16x8 b0 = *(const f16x8*)&Bs[0][wd * 32 + l31][ko];
            f16x8 b1 = *(const f16x8*)&Bs[1][wd * 32 + l31][ko];
            acc[0][0] = __builtin_amdgcn_mfma_f32_32x32x16_f16(a0, b0, acc[0][0], 0, 0, 0);
            acc[1][0] = __builtin_amdgcn_mfma_f32_32x32x16_f16(a1, b0, acc[1][0], 0, 0, 0);
            acc[0][1] = __builtin_amdgcn_mfma_f32_32x32x16_f16(a0, b1, acc[0][1], 0, 0, 0);
            acc[1][1] = __builtin_amdgcn_mfma_f32_32x32x16_f16(a1, b1, acc[1][1], 0, 0, 0);
        }
    }

    // epilogue: BN in regs -> LDS transpose tile -> coalesced float4 stores
    __syncthreads();                      // K-loop LDS reads done; safe to reuse
    {
        const int dl = wd * 32 + l31;     // local d row 0..63
#pragma unroll
        for (int ms = 0; ms < 2; ++ms)
#pragma unroll
        for (int r = 0; r < 16; ++r) {
            const int nl = wm * 64 + ms * 32 + (r & 3) + 8 * (r >> 2) + 4 * lhi;
            Pt[dl][nl] = (acc[ms][0][r] + acc[ms][1][r] * PSCALE_INV) * iv + ad;
        }
    }
    __syncthreads();
    {
        const int col4 = (tid & 31) * 4;  // float offset 0..124
        const int rw   = tid >> 5;        // 0..7
#pragma unroll
        for (int it = 0; it < 8; ++it) {
            const int row = rw + it * 8;  // 0..63
            float4 vv = *(const float4*)&Pt[row][col4];
            *(float4*)&out[((size_t)tb * C_ + d0 + row) * N_ + n0 + col4] = vv;
        }
    }
}

// ---------------------------------------------------------------------------
extern "C" void kernel_launch(void* const* d_in, const int* in_sizes, int n_in,
                              void* d_out, int out_size, void* d_ws, size_t ws_size,
                              hipStream_t stream)
{
    const float* x       = (const float*)d_in[0];
    const float* q_w     = (const float*)d_in[1];
    const float* q_gamma = (const float*)d_in[2];
    const float* q_beta  = (const float*)d_in[3];
    const float* q_mean  = (const float*)d_in[4];
    const float* q_var   = (const float*)d_in[5];
    const float* k_w     = (const float*)d_in[6];
    const float* k_gamma = (const float*)d_in[7];
    const float* k_beta  = (const float*)d_in[8];
    const float* k_mean  = (const float*)d_in[9];
    const float* k_var   = (const float*)d_in[10];
    const float* proj_w  = (const float*)d_in[11];
    const float* proj_b  = (const float*)d_in[12];
    const float* p_gamma = (const float*)d_in[13];
    const float* p_beta  = (const float*)d_in[14];
    const float* p_mean  = (const float*)d_in[15];
    const float* p_var   = (const float*)d_in[16];
    const float* m_alpha = (const float*)d_in[17];

    float* out = (float*)d_out;

    const size_t SPK_BYTES = (size_t)T_ * B_ * N_ * C_;          // u8
    const size_t W2_BYTES  = (size_t)2 * NW_ * sizeof(f16);
    const size_t TBHN      = (size_t)T_ * B_ * HEADS_ * N_;

    unsigned char* ws = (unsigned char*)d_ws;
    size_t off = 0;
    auto carve = [&](size_t bytes) {
        off = (off + 255) & ~(size_t)255;
        void* p = ws + off;
        off += bytes;
        return p;
    };
    unsigned char* s_u8  = (unsigned char*)carve(SPK_BYTES);
    unsigned char* q_spk = (unsigned char*)carve(SPK_BYTES);   // (t,b,n,C)
    unsigned char* k_spk = (unsigned char*)carve(SPK_BYTES);   // (t,b,n,C)
    f16* Wq2    = (f16*)carve(W2_BYTES);
    f16* Wk2    = (f16*)carve(W2_BYTES);
    f16* Wp2    = (f16*)carve(W2_BYTES);
    unsigned char* attn = (unsigned char*)carve(TBHN);

    // 1. input LIF (u8 spikes, z<32) + weight split over 144 blocks (z in [32,44))
    dim3 pgrid1(4, 3, 44);
    prep_kernel<<<pgrid1, 256, 0, stream>>>(x, s_u8, q_w, k_w, proj_w,
                                            Wq2, Wk2, Wp2);

    // 2. q+k GEMM + BN + in-register LIF (grid 256 x 12, round-11 version)
    dim3 qkgrid(256, 12);
    qk_gemm_lif_kernel<<<qkgrid, 256, 0, stream>>>(Wq2, Wk2, s_u8,
                                                   q_gamma, q_beta, q_mean, q_var,
                                                   k_gamma, k_beta, k_mean, k_var,
                                                   q_spk, k_spk);

    // 3. fused head-sum + memory + attn LIF
    head_attn_kernel<<<(B_ * HEADS_ * N_) / 256, 256, 0, stream>>>(q_spk, m_alpha, attn);

    // 4. proj GEMM -> out (grid 256 x 6)
    dim3 pjgrid(256, 6);
    proj_gemm_kernel<<<pjgrid, 256, 0, stream>>>(Wp2, k_spk, attn, proj_b,
                                                 p_gamma, p_beta, p_mean, p_var, out);
}